// Round 3
// baseline (618.623 us; speedup 1.0000x reference)
//
#include <hip/hip_runtime.h>
#include <stdint.h>

// CIN (xDeepFM): B=1024, F=39, D=64, UNITS=[128,128,128]
// Out[b, o, d] = sum_{h,m} W[o, h*M+m] * X0[b,h,d] * Xi[b,m,d]
// Restructure: Out = sum_h x0_h[d] * (W_h @ Xi)   -- 39 bf16 GEMMs + fp32 scale
// One block per b; block tile 128(o) x 64(d); 4 waves, each 32(o) x 64(d).

#define F_N 39
#define D_N 64
#define O_N 128

typedef __attribute__((ext_vector_type(8))) short short8;  // 8 bf16 in 4 VGPRs
typedef __attribute__((ext_vector_type(4))) float f32x4;

__device__ __forceinline__ unsigned short f2bf(float f) {
  union { float f; uint32_t u; } v; v.f = f;
  uint32_t u = v.u;
  u += 0x7FFFu + ((u >> 16) & 1u);   // round-to-nearest-even
  return (unsigned short)(u >> 16);
}

// f32 -> bf16 vectorized convert (also used for W2/W3)
__global__ __launch_bounds__(256) void cvt_bf16_k(const float* __restrict__ x,
                                                  unsigned short* __restrict__ y, int n4) {
  int i = blockIdx.x * 256 + threadIdx.x;
  if (i < n4) {
    float4 v = reinterpret_cast<const float4*>(x)[i];
    ushort4 o;
    o.x = f2bf(v.x); o.y = f2bf(v.y); o.z = f2bf(v.z); o.w = f2bf(v.w);
    reinterpret_cast<ushort4*>(y)[i] = o;
  }
}

// W1 [128][39*39] f32 -> padded [128][39*64] bf16 (m in 39..63 zero)
__global__ __launch_bounds__(256) void repack_w1_k(const float* __restrict__ w,
                                                   unsigned short* __restrict__ y) {
  int i = blockIdx.x * 256 + threadIdx.x;   // i < 128*39*64 = 319488
  int m = i & 63;
  int h = (i >> 6) % 39;
  int o = i / (39 * 64);
  y[i] = (m < 39) ? f2bf(w[o * 1521 + h * 39 + m]) : (unsigned short)0;
}

// MP: padded channel count of Xi (64 for layer1, 128 for layers 2/3)
// LOFF: column offset into out [1024][384]; WRITE_X: store X_next bf16
template <int MP, int LOFF, bool WRITE_X>
__global__ __launch_bounds__(256) void cin_layer_k(
    const unsigned short* __restrict__ Xib, int Mv,            // [B][Mv][64] bf16
    const unsigned short* __restrict__ Wb,                     // [128][39*MP] bf16
    const float* __restrict__ X0f,                             // [B][39][64] f32
    const float* __restrict__ bias,                            // [128] f32
    unsigned short* __restrict__ Xnext,                        // [B][128][64] bf16
    float* __restrict__ out)                                   // [B][384] f32
{
  __shared__ __align__(16) unsigned short xi_t[8192]; // 16 KB: [d=64][m=MP] bf16, XOR-swizzled
  __shared__ float x0s[F_N * D_N];                    // 9984 B: [h][d] f32

  const int b = blockIdx.x;
  const int t = threadIdx.x;

  // ---- stage Xi transposed+swizzled, X0 fp32 ----
  {
    const int d = t & 63, m0 = t >> 6;
    const unsigned short* src = Xib + (size_t)b * Mv * 64;
    #pragma unroll
    for (int m = m0; m < MP; m += 4) {
      unsigned short v = (m < Mv) ? src[m * 64 + d] : (unsigned short)0;
      int off = (d * (MP * 2) + m * 2) ^ ((d & 7) << 4);
      *(unsigned short*)((char*)xi_t + off) = v;
    }
    const float* xs = X0f + (size_t)b * (F_N * D_N);
    for (int i = t; i < F_N * D_N; i += 256) x0s[i] = xs[i];
  }
  __syncthreads();

  const int wave = t >> 6, lane = t & 63, lr = lane & 15, lg = lane >> 4;
  const int KS = MP / 32;
  const f32x4 zero4 = {0.f, 0.f, 0.f, 0.f};

  f32x4 accO[2][4];
  #pragma unroll
  for (int i = 0; i < 2; ++i)
    #pragma unroll
    for (int j = 0; j < 4; ++j) accO[i][j] = zero4;

  // A-frag rows: o = wave*32 + of*16 + lr ; cols k = h*MP + kk*32 + lg*8 + j
  const unsigned short* w0 = Wb + (size_t)(wave * 32 + lr) * (F_N * MP);
  const unsigned short* w1 = w0 + (size_t)16 * (F_N * MP);

  for (int h = 0; h < F_N; ++h) {
    f32x4 accP[2][4];
    #pragma unroll
    for (int i = 0; i < 2; ++i)
      #pragma unroll
      for (int j = 0; j < 4; ++j) accP[i][j] = zero4;

    #pragma unroll
    for (int kk = 0; kk < KS; ++kk) {
      const int kc = h * MP + kk * 32 + lg * 8;
      short8 a0 = *(const short8*)(w0 + kc);
      short8 a1 = *(const short8*)(w1 + kc);
      #pragma unroll
      for (int nf = 0; nf < 4; ++nf) {
        const int n = nf * 16 + lr;
        const int off = (n * (MP * 2) + (kk * 32 + lg * 8) * 2) ^ ((n & 7) << 4);
        short8 bb = *(const short8*)((const char*)xi_t + off);
        accP[0][nf] = __builtin_amdgcn_mfma_f32_16x16x32_bf16(a0, bb, accP[0][nf], 0, 0, 0);
        accP[1][nf] = __builtin_amdgcn_mfma_f32_16x16x32_bf16(a1, bb, accP[1][nf], 0, 0, 0);
      }
    }
    // fp32 scale-accumulate: accO += x0[h][n] * accP
    #pragma unroll
    for (int nf = 0; nf < 4; ++nf) {
      const float s = x0s[h * 64 + nf * 16 + lr];
      #pragma unroll
      for (int of = 0; of < 2; ++of)
        #pragma unroll
        for (int r = 0; r < 4; ++r) accO[of][nf][r] += s * accP[of][nf][r];
    }
  }

  // ---- epilogue ----
  float bv[2][4];
  #pragma unroll
  for (int of = 0; of < 2; ++of)
    #pragma unroll
    for (int r = 0; r < 4; ++r) bv[of][r] = bias[wave * 32 + of * 16 + lg * 4 + r];

  if (WRITE_X) {
    __syncthreads();  // xi_t no longer needed; reuse as [128][64] bf16 staging
    unsigned short* xo = xi_t;
    #pragma unroll
    for (int of = 0; of < 2; ++of)
      #pragma unroll
      for (int nf = 0; nf < 4; ++nf)
        #pragma unroll
        for (int r = 0; r < 4; ++r) {
          int o = wave * 32 + of * 16 + lg * 4 + r;
          xo[o * 64 + nf * 16 + lr] = f2bf(accO[of][nf][r] + bv[of][r]);
        }
    __syncthreads();
    const uint4* s4 = (const uint4*)xo;
    uint4* d4 = (uint4*)(Xnext + (size_t)b * (O_N * D_N));
    for (int i = t; i < 1024; i += 256) d4[i] = s4[i];  // 16 KB coalesced
  }

  // pooled[b][o] = sum_d Out + 64*bias
  #pragma unroll
  for (int of = 0; of < 2; ++of)
    #pragma unroll
    for (int r = 0; r < 4; ++r) {
      float p = accO[of][0][r] + accO[of][1][r] + accO[of][2][r] + accO[of][3][r];
      p += __shfl_xor(p, 1, 16);
      p += __shfl_xor(p, 2, 16);
      p += __shfl_xor(p, 4, 16);
      p += __shfl_xor(p, 8, 16);
      if (lr == 0)
        out[(size_t)b * 384 + LOFF + wave * 32 + of * 16 + lg * 4 + r] = p + 64.0f * bv[of][r];
    }
}

extern "C" void kernel_launch(void* const* d_in, const int* in_sizes, int n_in,
                              void* d_out, int out_size, void* d_ws, size_t ws_size,
                              hipStream_t stream) {
  const float* X0 = (const float*)d_in[0];
  const float* W1 = (const float*)d_in[1];
  const float* b1 = (const float*)d_in[2];
  const float* W2 = (const float*)d_in[3];
  const float* b2 = (const float*)d_in[4];
  const float* W3 = (const float*)d_in[5];
  const float* b3 = (const float*)d_in[6];
  float* out = (float*)d_out;

  // ws layout (bf16 elements): total ~42 MB
  unsigned short* X0b = (unsigned short*)d_ws;      // 1024*39*64   = 2555904
  unsigned short* W1p = X0b + 2555904;              // 128*39*64    = 319488
  unsigned short* W2b = W1p + 319488;               // 128*4992     = 638976
  unsigned short* W3b = W2b + 638976;
  unsigned short* X1b = W3b + 638976;               // 1024*128*64  = 8388608
  unsigned short* X2b = X1b + 8388608;

  cvt_bf16_k<<<2496, 256, 0, stream>>>(X0, X0b, 638976);   // 2555904/4
  repack_w1_k<<<1248, 256, 0, stream>>>(W1, W1p);
  cvt_bf16_k<<<624, 256, 0, stream>>>(W2, W2b, 159744);    // 638976/4
  cvt_bf16_k<<<624, 256, 0, stream>>>(W3, W3b, 159744);

  cin_layer_k<64, 0, true><<<1024, 256, 0, stream>>>(X0b, 39, W1p, X0, b1, X1b, out);
  cin_layer_k<128, 128, true><<<1024, 256, 0, stream>>>(X1b, 128, W2b, X0, b2, X2b, out);
  cin_layer_k<128, 256, false><<<1024, 256, 0, stream>>>(X2b, 128, W3b, X0, b3, X1b, out);
}

// Round 5
// 368.739 us; speedup vs baseline: 1.6777x; 1.6777x over previous
//
#include <hip/hip_runtime.h>
#include <stdint.h>

// CIN (xDeepFM): B=1024, F=39, D=64, UNITS=[128,128,128]
// Out[b,o,d] = sum_{h,m} W[o,h*M+m] * X0[b,h,d] * Xi[b,m,d]
//            = sum_h x0_h[d] * (W_h @ Xi)    (39 bf16 GEMMs + fp32 scale)
// One block per b; 4 waves, each 32(o) x 64(d).
// R4: B-frags hoisted out of h-loop (h-invariant!), W pre-packed into
// fragment-contiguous layout (coalesced dwordx4), explicit 2-deep register
// double-buffer on W across h (issue-early / consume-late).

#define F_N 39
#define D_N 64
#define O_N 128

typedef __attribute__((ext_vector_type(8))) short short8;  // 8 bf16, 4 VGPRs
typedef __attribute__((ext_vector_type(4))) float f32x4;

__device__ __forceinline__ unsigned short f2bf(float f) {
  union { float f; uint32_t u; } v; v.f = f;
  uint32_t u = v.u;
  u += 0x7FFFu + ((u >> 16) & 1u);   // round-to-nearest-even
  return (unsigned short)(u >> 16);
}

// f32 -> bf16 vectorized convert (X0)
__global__ __launch_bounds__(256) void cvt_bf16_k(const float* __restrict__ x,
                                                  unsigned short* __restrict__ y, int n4) {
  int i = blockIdx.x * 256 + threadIdx.x;
  if (i < n4) {
    float4 v = reinterpret_cast<const float4*>(x)[i];
    ushort4 o;
    o.x = f2bf(v.x); o.y = f2bf(v.y); o.z = f2bf(v.z); o.w = f2bf(v.w);
    reinterpret_cast<ushort4*>(y)[i] = o;
  }
}

// W [128][39*Mv] f32 -> fragment-contiguous bf16:
// y[ ((((h*KS+kk)*4 + wave)*2 + p)*64 + lane)*8 + j ]
//   = W[ wave*32+p*16+(lane&15) ][ h*Mv + kk*32+(lane>>4)*8+j ]   (0 if m>=Mv)
template <int KS, int Mv>
__global__ __launch_bounds__(256) void repack_wf_k(const float* __restrict__ w,
                                                   unsigned short* __restrict__ y, int total) {
  int idx = blockIdx.x * 256 + threadIdx.x;
  if (idx >= total) return;
  int j = idx & 7, lane = (idx >> 3) & 63, p = (idx >> 9) & 1, wv = (idx >> 10) & 3;
  int kkh = idx >> 12, kk = kkh % KS, h = kkh / KS;
  int o = wv * 32 + p * 16 + (lane & 15);
  int m = kk * 32 + (lane >> 4) * 8 + j;
  float v = (m < Mv) ? w[(size_t)o * (39 * Mv) + h * Mv + m] : 0.f;
  y[idx] = f2bf(v);
}

// MP: padded channel count of Xi (64 layer1, 128 layers 2/3); KS = MP/32
// LOFF: column offset into out [1024][384]; WRITE_X: store X_next bf16
template <int MP, int LOFF, bool WRITE_X>
__global__ __launch_bounds__(256) void cin_layer_k(
    const unsigned short* __restrict__ Xib, int Mv,            // [B][Mv][64] bf16
    const unsigned short* __restrict__ Wfrag,                  // fragment-packed bf16
    const float* __restrict__ X0f,                             // [B][39][64] f32
    const float* __restrict__ bias,                            // [128] f32
    unsigned short* __restrict__ Xnext,                        // [B][128][64] bf16
    float* __restrict__ out)                                   // [B][384] f32
{
  constexpr int KS = MP / 32;
  __shared__ __align__(16) unsigned short xi_t[8192]; // 16 KB, [d][m] XOR-swizzled
  __shared__ float x0s[F_N * D_N];                    // [h][d] f32

  const int b = blockIdx.x;
  const int t = threadIdx.x;

  // ---- stage Xi transposed+swizzled, X0 fp32 ----
  {
    const int d = t & 63, m0 = t >> 6;
    const unsigned short* src = Xib + (size_t)b * Mv * 64;
    #pragma unroll
    for (int m = m0; m < MP; m += 4) {
      unsigned short v = (m < Mv) ? src[m * 64 + d] : (unsigned short)0;
      int off = (d * (MP * 2) + m * 2) ^ ((d & 7) << 4);
      *(unsigned short*)((char*)xi_t + off) = v;
    }
    const float* xs = X0f + (size_t)b * (F_N * D_N);
    for (int i = t; i < F_N * D_N; i += 256) x0s[i] = xs[i];
  }
  __syncthreads();

  const int wave = t >> 6, lane = t & 63, lr = lane & 15, lg = lane >> 4;
  const f32x4 zero4 = {0.f, 0.f, 0.f, 0.f};

  // ---- hoist B-fragments (h-invariant!): bbr[kk][nf], 4*KS short8 ----
  short8 bbr[KS][4];
  #pragma unroll
  for (int kk = 0; kk < KS; ++kk)
    #pragma unroll
    for (int nf = 0; nf < 4; ++nf) {
      const int n = nf * 16 + lr;
      const int off = (n * (MP * 2) + (kk * 32 + lg * 8) * 2) ^ ((n & 7) << 4);
      bbr[kk][nf] = *(const short8*)((const char*)xi_t + off);
    }

  f32x4 accO[2][4];
  #pragma unroll
  for (int p = 0; p < 2; ++p)
    #pragma unroll
    for (int nf = 0; nf < 4; ++nf) accO[p][nf] = zero4;

  // W fragment slots (16B units): slot = (((h*KS+kk)*4+wave)*2+p)*64 + lane
  const short8* Wf = (const short8*)Wfrag;
  const int wbase = wave * 128 + lane;

  short8 wA[KS][2], wB[KS][2];

  auto loadW = [&](short8 (&buf)[KS][2], int hh) {
    const short8* pw = Wf + (size_t)hh * (KS * 512) + wbase;
    #pragma unroll
    for (int kk = 0; kk < KS; ++kk)
      #pragma unroll
      for (int p = 0; p < 2; ++p)
        buf[kk][p] = pw[kk * 512 + p * 64];
  };

  auto body = [&](short8 (&buf)[KS][2], int h) {
    f32x4 accP[2][4];
    #pragma unroll
    for (int p = 0; p < 2; ++p)
      #pragma unroll
      for (int nf = 0; nf < 4; ++nf)
        accP[p][nf] = __builtin_amdgcn_mfma_f32_16x16x32_bf16(buf[0][p], bbr[0][nf], zero4, 0, 0, 0);
    #pragma unroll
    for (int kk = 1; kk < KS; ++kk)
      #pragma unroll
      for (int p = 0; p < 2; ++p)
        #pragma unroll
        for (int nf = 0; nf < 4; ++nf)
          accP[p][nf] = __builtin_amdgcn_mfma_f32_16x16x32_bf16(buf[kk][p], bbr[kk][nf], accP[p][nf], 0, 0, 0);
    #pragma unroll
    for (int nf = 0; nf < 4; ++nf) {
      const float s = x0s[h * 64 + nf * 16 + lr];
      #pragma unroll
      for (int p = 0; p < 2; ++p)
        #pragma unroll
        for (int r = 0; r < 4; ++r) accO[p][nf][r] += s * accP[p][nf][r];
    }
  };

  // ---- software-pipelined h-loop (static 2-buffer, unroll-2) ----
  loadW(wA, 0);
  for (int h = 0; h < F_N; h += 2) {
    loadW(wB, (h + 1 < F_N) ? h + 1 : F_N - 1);
    body(wA, h);
    loadW(wA, (h + 2 < F_N) ? h + 2 : F_N - 1);
    if (h + 1 < F_N) body(wB, h + 1);
  }

  // ---- epilogue ----
  float bv[2][4];
  #pragma unroll
  for (int p = 0; p < 2; ++p)
    #pragma unroll
    for (int r = 0; r < 4; ++r) bv[p][r] = bias[wave * 32 + p * 16 + lg * 4 + r];

  if (WRITE_X) {
    __syncthreads();  // xi_t no longer needed; reuse as [128][64] bf16 staging
    unsigned short* xo = xi_t;
    #pragma unroll
    for (int p = 0; p < 2; ++p)
      #pragma unroll
      for (int nf = 0; nf < 4; ++nf)
        #pragma unroll
        for (int r = 0; r < 4; ++r) {
          int o = wave * 32 + p * 16 + lg * 4 + r;
          xo[o * 64 + nf * 16 + lr] = f2bf(accO[p][nf][r] + bv[p][r]);
        }
    __syncthreads();
    const uint4* s4 = (const uint4*)xo;
    uint4* d4 = (uint4*)(Xnext + (size_t)b * (O_N * D_N));
    for (int i = t; i < 1024; i += 256) d4[i] = s4[i];  // 16 KB coalesced
  }

  // pooled[b][o] = sum_d Out + 64*bias
  #pragma unroll
  for (int p = 0; p < 2; ++p)
    #pragma unroll
    for (int r = 0; r < 4; ++r) {
      float v = accO[p][0][r] + accO[p][1][r] + accO[p][2][r] + accO[p][3][r];
      v += __shfl_xor(v, 1, 16);
      v += __shfl_xor(v, 2, 16);
      v += __shfl_xor(v, 4, 16);
      v += __shfl_xor(v, 8, 16);
      if (lr == 0)
        out[(size_t)b * 384 + LOFF + wave * 32 + p * 16 + lg * 4 + r] = v + 64.0f * bv[p][r];
    }
}

extern "C" void kernel_launch(void* const* d_in, const int* in_sizes, int n_in,
                              void* d_out, int out_size, void* d_ws, size_t ws_size,
                              hipStream_t stream) {
  const float* X0 = (const float*)d_in[0];
  const float* W1 = (const float*)d_in[1];
  const float* b1 = (const float*)d_in[2];
  const float* W2 = (const float*)d_in[3];
  const float* b2 = (const float*)d_in[4];
  const float* W3 = (const float*)d_in[5];
  const float* b3 = (const float*)d_in[6];
  float* out = (float*)d_out;

  // ws layout (bf16 elements): ~42 MB
  unsigned short* X0b = (unsigned short*)d_ws;      // 1024*39*64   = 2555904
  unsigned short* W1f = X0b + 2555904;              // 39*2*4096    = 319488
  unsigned short* W2f = W1f + 319488;               // 39*4*4096    = 638976
  unsigned short* W3f = W2f + 638976;
  unsigned short* X1b = W3f + 638976;               // 1024*128*64  = 8388608
  unsigned short* X2b = X1b + 8388608;

  cvt_bf16_k<<<2496, 256, 0, stream>>>(X0, X0b, 638976);            // 2555904/4
  repack_wf_k<2, 39><<<1248, 256, 0, stream>>>(W1, W1f, 319488);
  repack_wf_k<4, 128><<<2496, 256, 0, stream>>>(W2, W2f, 638976);
  repack_wf_k<4, 128><<<2496, 256, 0, stream>>>(W3, W3f, 638976);

  cin_layer_k<64, 0, true><<<1024, 256, 0, stream>>>(X0b, 39, W1f, X0, b1, X1b, out);
  cin_layer_k<128, 128, true><<<1024, 256, 0, stream>>>(X1b, 128, W2f, X0, b2, X2b, out);
  cin_layer_k<128, 256, false><<<1024, 256, 0, stream>>>(X2b, 128, W3f, X0, b3, X1b, out);
}

// Round 6
// 325.086 us; speedup vs baseline: 1.9030x; 1.1343x over previous
//
#include <hip/hip_runtime.h>
#include <stdint.h>

// CIN (xDeepFM): B=1024, F=39, D=64, UNITS=[128,128,128]
// Layers 1/2: Out = sum_h x0_h[d] * (W_h @ Xi)  (bf16 MFMA + fp32 scale)
// Layer 3 (pooled-only) COLLAPSED: pooled3[b,o] = sum_k W3[o,k]*G[b,k],
//   G[b,h,m] = sum_d X0[b,h,d]*X2[b,m,d]   (84 GFLOP -> ~2 GFLOP)

#define F_N 39
#define D_N 64
#define O_N 128

typedef __attribute__((ext_vector_type(8))) short short8;  // 8 bf16, 4 VGPRs
typedef __attribute__((ext_vector_type(4))) float f32x4;

__device__ __forceinline__ unsigned short f2bf(float f) {
  union { float f; uint32_t u; } v; v.f = f;
  uint32_t u = v.u;
  u += 0x7FFFu + ((u >> 16) & 1u);   // round-to-nearest-even
  return (unsigned short)(u >> 16);
}

// f32 -> bf16 vectorized convert (X0, W3)
__global__ __launch_bounds__(256) void cvt_bf16_k(const float* __restrict__ x,
                                                  unsigned short* __restrict__ y, int n4) {
  int i = blockIdx.x * 256 + threadIdx.x;
  if (i < n4) {
    float4 v = reinterpret_cast<const float4*>(x)[i];
    ushort4 o;
    o.x = f2bf(v.x); o.y = f2bf(v.y); o.z = f2bf(v.z); o.w = f2bf(v.w);
    reinterpret_cast<ushort4*>(y)[i] = o;
  }
}

// W [128][39*Mv] f32 -> fragment-contiguous bf16 (layers 1/2):
// y[ ((((h*KS+kk)*4 + wave)*2 + p)*64 + lane)*8 + j ]
//   = W[ wave*32+p*16+(lane&15) ][ h*Mv + kk*32+(lane>>4)*8+j ]   (0 if m>=Mv)
template <int KS, int Mv>
__global__ __launch_bounds__(256) void repack_wf_k(const float* __restrict__ w,
                                                   unsigned short* __restrict__ y, int total) {
  int idx = blockIdx.x * 256 + threadIdx.x;
  if (idx >= total) return;
  int j = idx & 7, lane = (idx >> 3) & 63, p = (idx >> 9) & 1, wv = (idx >> 10) & 3;
  int kkh = idx >> 12, kk = kkh % KS, h = kkh / KS;
  int o = wv * 32 + p * 16 + (lane & 15);
  int m = kk * 32 + (lane >> 4) * 8 + j;
  float v = (m < Mv) ? w[(size_t)o * (39 * Mv) + h * Mv + m] : 0.f;
  y[idx] = f2bf(v);
}

// MP: padded channel count of Xi (64 layer1, 128 layer2); KS = MP/32
template <int MP, int LOFF, bool WRITE_X>
__global__ __launch_bounds__(256) void cin_layer_k(
    const unsigned short* __restrict__ Xib, int Mv,            // [B][Mv][64] bf16
    const unsigned short* __restrict__ Wfrag,                  // fragment-packed bf16
    const float* __restrict__ X0f,                             // [B][39][64] f32
    const float* __restrict__ bias,                            // [128] f32
    unsigned short* __restrict__ Xnext,                        // [B][128][64] bf16
    float* __restrict__ out)                                   // [B][384] f32
{
  constexpr int KS = MP / 32;
  __shared__ __align__(16) unsigned short xi_t[8192]; // 16 KB, [d][m] XOR-swizzled
  __shared__ float x0s[F_N * D_N];                    // [h][d] f32

  const int b = blockIdx.x;
  const int t = threadIdx.x;

  // ---- stage Xi transposed+swizzled, X0 fp32 ----
  {
    const int d = t & 63, m0 = t >> 6;
    const unsigned short* src = Xib + (size_t)b * Mv * 64;
    #pragma unroll
    for (int m = m0; m < MP; m += 4) {
      unsigned short v = (m < Mv) ? src[m * 64 + d] : (unsigned short)0;
      int off = (d * (MP * 2) + m * 2) ^ ((d & 7) << 4);
      *(unsigned short*)((char*)xi_t + off) = v;
    }
    const float* xs = X0f + (size_t)b * (F_N * D_N);
    for (int i = t; i < F_N * D_N; i += 256) x0s[i] = xs[i];
  }
  __syncthreads();

  const int wave = t >> 6, lane = t & 63, lr = lane & 15, lg = lane >> 4;
  const f32x4 zero4 = {0.f, 0.f, 0.f, 0.f};

  // ---- hoist B-fragments (h-invariant!): bbr[kk][nf] ----
  short8 bbr[KS][4];
  #pragma unroll
  for (int kk = 0; kk < KS; ++kk)
    #pragma unroll
    for (int nf = 0; nf < 4; ++nf) {
      const int n = nf * 16 + lr;
      const int off = (n * (MP * 2) + (kk * 32 + lg * 8) * 2) ^ ((n & 7) << 4);
      bbr[kk][nf] = *(const short8*)((const char*)xi_t + off);
    }

  f32x4 accO[2][4];
  #pragma unroll
  for (int p = 0; p < 2; ++p)
    #pragma unroll
    for (int nf = 0; nf < 4; ++nf) accO[p][nf] = zero4;

  const short8* Wf = (const short8*)Wfrag;
  const int wbase = wave * 128 + lane;

  short8 wA[KS][2], wB[KS][2];

  auto loadW = [&](short8 (&buf)[KS][2], int hh) {
    const short8* pw = Wf + (size_t)hh * (KS * 512) + wbase;
    #pragma unroll
    for (int kk = 0; kk < KS; ++kk)
      #pragma unroll
      for (int p = 0; p < 2; ++p)
        buf[kk][p] = pw[kk * 512 + p * 64];
  };

  auto body = [&](short8 (&buf)[KS][2], int h) {
    f32x4 accP[2][4];
    #pragma unroll
    for (int p = 0; p < 2; ++p)
      #pragma unroll
      for (int nf = 0; nf < 4; ++nf)
        accP[p][nf] = __builtin_amdgcn_mfma_f32_16x16x32_bf16(buf[0][p], bbr[0][nf], zero4, 0, 0, 0);
    #pragma unroll
    for (int kk = 1; kk < KS; ++kk)
      #pragma unroll
      for (int p = 0; p < 2; ++p)
        #pragma unroll
        for (int nf = 0; nf < 4; ++nf)
          accP[p][nf] = __builtin_amdgcn_mfma_f32_16x16x32_bf16(buf[kk][p], bbr[kk][nf], accP[p][nf], 0, 0, 0);
    #pragma unroll
    for (int nf = 0; nf < 4; ++nf) {
      const float s = x0s[h * 64 + nf * 16 + lr];
      #pragma unroll
      for (int p = 0; p < 2; ++p)
        #pragma unroll
        for (int r = 0; r < 4; ++r) accO[p][nf][r] += s * accP[p][nf][r];
    }
  };

  // ---- software-pipelined h-loop (static 2-buffer, unroll-2) ----
  loadW(wA, 0);
  for (int h = 0; h < F_N; h += 2) {
    loadW(wB, (h + 1 < F_N) ? h + 1 : F_N - 1);
    body(wA, h);
    loadW(wA, (h + 2 < F_N) ? h + 2 : F_N - 1);
    if (h + 1 < F_N) body(wB, h + 1);
  }

  // ---- epilogue ----
  float bv[2][4];
  #pragma unroll
  for (int p = 0; p < 2; ++p)
    #pragma unroll
    for (int r = 0; r < 4; ++r) bv[p][r] = bias[wave * 32 + p * 16 + lg * 4 + r];

  if (WRITE_X) {
    __syncthreads();
    unsigned short* xo = xi_t;
    #pragma unroll
    for (int p = 0; p < 2; ++p)
      #pragma unroll
      for (int nf = 0; nf < 4; ++nf)
        #pragma unroll
        for (int r = 0; r < 4; ++r) {
          int o = wave * 32 + p * 16 + lg * 4 + r;
          xo[o * 64 + nf * 16 + lr] = f2bf(accO[p][nf][r] + bv[p][r]);
        }
    __syncthreads();
    const uint4* s4 = (const uint4*)xo;
    uint4* d4 = (uint4*)(Xnext + (size_t)b * (O_N * D_N));
    for (int i = t; i < 1024; i += 256) d4[i] = s4[i];
  }

  #pragma unroll
  for (int p = 0; p < 2; ++p)
    #pragma unroll
    for (int r = 0; r < 4; ++r) {
      float v = accO[p][0][r] + accO[p][1][r] + accO[p][2][r] + accO[p][3][r];
      v += __shfl_xor(v, 1, 16);
      v += __shfl_xor(v, 2, 16);
      v += __shfl_xor(v, 4, 16);
      v += __shfl_xor(v, 8, 16);
      if (lr == 0)
        out[(size_t)b * 384 + LOFF + wave * 32 + p * 16 + lg * 4 + r] = v + 64.0f * bv[p][r];
    }
}

// G[b,h,m] = sum_d X0[b,h,d]*X2[b,m,d]  -> Gb [1024][39*128] bf16
// One block per b; wave handles m-slice of 32 (2 mf frags), all h (3 hf frags).
__global__ __launch_bounds__(256) void gram_k(
    const unsigned short* __restrict__ X0b,   // [1024][39][64] bf16
    const unsigned short* __restrict__ X2b,   // [1024][128][64] bf16
    unsigned short* __restrict__ Gb)          // [1024][4992] bf16
{
  const int b = blockIdx.x, t = threadIdx.x;
  const int wave = t >> 6, lane = t & 63, lr = lane & 15, lg = lane >> 4;
  const f32x4 zero4 = {0.f, 0.f, 0.f, 0.f};

  const unsigned short* xa = X0b + (size_t)b * 2496;
  const unsigned short* xc = X2b + (size_t)b * 8192;

  short8 af[3][2], bfr[2][2];
  #pragma unroll
  for (int hf = 0; hf < 3; ++hf)       // A row = h (rows 39..47 read garbage, masked at store)
    #pragma unroll
    for (int kk = 0; kk < 2; ++kk)
      af[hf][kk] = *(const short8*)(xa + (hf * 16 + lr) * 64 + kk * 32 + lg * 8);
  #pragma unroll
  for (int mf = 0; mf < 2; ++mf)       // B col = m
    #pragma unroll
    for (int kk = 0; kk < 2; ++kk)
      bfr[mf][kk] = *(const short8*)(xc + (wave * 32 + mf * 16 + lr) * 64 + kk * 32 + lg * 8);

  f32x4 acc[3][2];
  #pragma unroll
  for (int hf = 0; hf < 3; ++hf)
    #pragma unroll
    for (int mf = 0; mf < 2; ++mf) {
      acc[hf][mf] = __builtin_amdgcn_mfma_f32_16x16x32_bf16(af[hf][0], bfr[mf][0], zero4, 0, 0, 0);
      acc[hf][mf] = __builtin_amdgcn_mfma_f32_16x16x32_bf16(af[hf][1], bfr[mf][1], acc[hf][mf], 0, 0, 0);
    }

  // D: row(h) = hf*16 + lg*4 + r, col(m) = wave*32 + mf*16 + lr
  #pragma unroll
  for (int hf = 0; hf < 3; ++hf)
    #pragma unroll
    for (int mf = 0; mf < 2; ++mf)
      #pragma unroll
      for (int r = 0; r < 4; ++r) {
        int h = hf * 16 + lg * 4 + r;
        if (h < F_N)
          Gb[(size_t)b * 4992 + h * 128 + wave * 32 + mf * 16 + lr] = f2bf(acc[hf][mf][r]);
      }
}

// pooled3[b,o] = sum_k W3[o,k]*G[b,k] + 64*b3[o]; K=4992=156*32
// Grid 64 blocks x 16 b; wave handles o-slice of 32 (2 frags), 16 b rows.
__global__ __launch_bounds__(256) void pooled3_k(
    const unsigned short* __restrict__ Gb,    // [1024][4992] bf16
    const unsigned short* __restrict__ W3p,   // [128][4992] bf16
    const float* __restrict__ b3,             // [128] f32
    float* __restrict__ out)                  // [1024][384] f32
{
  const int b0 = blockIdx.x * 16, t = threadIdx.x;
  const int wave = t >> 6, lane = t & 63, lr = lane & 15, lg = lane >> 4;
  const f32x4 zero4 = {0.f, 0.f, 0.f, 0.f};

  const unsigned short* ga = Gb + (size_t)(b0 + lr) * 4992 + lg * 8;   // A row = b
  const unsigned short* w0 = W3p + (size_t)(wave * 32 + lr) * 4992 + lg * 8; // B col = o
  const unsigned short* w1 = w0 + (size_t)16 * 4992;

  f32x4 acc0 = zero4, acc1 = zero4;
  #pragma unroll 4
  for (int ks = 0; ks < 156; ++ks) {
    short8 a  = *(const short8*)(ga + ks * 32);
    short8 q0 = *(const short8*)(w0 + ks * 32);
    short8 q1 = *(const short8*)(w1 + ks * 32);
    acc0 = __builtin_amdgcn_mfma_f32_16x16x32_bf16(a, q0, acc0, 0, 0, 0);
    acc1 = __builtin_amdgcn_mfma_f32_16x16x32_bf16(a, q1, acc1, 0, 0, 0);
  }

  // D: row(b) = lg*4 + r, col(o) = lr (+ frag offset)
  #pragma unroll
  for (int r = 0; r < 4; ++r) {
    int bb = b0 + lg * 4 + r;
    int o0 = wave * 32 + lr;
    out[(size_t)bb * 384 + 256 + o0]      = acc0[r] + 64.0f * b3[o0];
    out[(size_t)bb * 384 + 256 + o0 + 16] = acc1[r] + 64.0f * b3[o0 + 16];
  }
}

extern "C" void kernel_launch(void* const* d_in, const int* in_sizes, int n_in,
                              void* d_out, int out_size, void* d_ws, size_t ws_size,
                              hipStream_t stream) {
  const float* X0 = (const float*)d_in[0];
  const float* W1 = (const float*)d_in[1];
  const float* b1 = (const float*)d_in[2];
  const float* W2 = (const float*)d_in[3];
  const float* b2 = (const float*)d_in[4];
  const float* W3 = (const float*)d_in[5];
  const float* b3 = (const float*)d_in[6];
  float* out = (float*)d_out;

  // ws layout (bf16 elements) — identical footprint to round 5 (~42 MB)
  unsigned short* X0b = (unsigned short*)d_ws;      // 1024*39*64   = 2555904
  unsigned short* W1f = X0b + 2555904;              // 39*2*4096    = 319488
  unsigned short* W2f = W1f + 319488;               // 39*4*4096    = 638976
  unsigned short* W3p = W2f + 638976;               // 128*4992     = 638976 (plain bf16)
  unsigned short* X1b = W3p + 638976;               // 1024*128*64  = 8388608
  unsigned short* X2b = X1b + 8388608;
  unsigned short* Gb  = X1b;                        // alias: X1b free after layer 2

  cvt_bf16_k<<<2496, 256, 0, stream>>>(X0, X0b, 638976);
  repack_wf_k<2, 39><<<1248, 256, 0, stream>>>(W1, W1f, 319488);
  repack_wf_k<4, 128><<<2496, 256, 0, stream>>>(W2, W2f, 638976);
  cvt_bf16_k<<<624, 256, 0, stream>>>(W3, W3p, 159744);

  cin_layer_k<64, 0, true><<<1024, 256, 0, stream>>>(X0b, 39, W1f, X0, b1, X1b, out);
  cin_layer_k<128, 128, true><<<1024, 256, 0, stream>>>(X1b, 128, W2f, X0, b2, X2b, out);
  gram_k<<<1024, 256, 0, stream>>>(X0b, X2b, Gb);
  pooled3_k<<<64, 256, 0, stream>>>(Gb, W3p, b3, out);
}

// Round 7
// 291.627 us; speedup vs baseline: 2.1213x; 1.1147x over previous
//
#include <hip/hip_runtime.h>
#include <stdint.h>

// CIN (xDeepFM): B=1024, F=39, D=64, UNITS=[128,128,128]
// Layers 1/2: Out = sum_h x0_h[d] * (W_h @ Xi)  (bf16 MFMA + fp32 scale)
// Layer 3 (pooled-only) COLLAPSED: pooled3[b,o] = sum_k W3[o,k]*G[b,k],
//   G[b,h,m] = sum_d X0[b,h,d]*X2[b,m,d]
// R7: __launch_bounds__(256,2) on cin_layer_k -> 256-VGPR budget, no spill.

#define F_N 39
#define D_N 64
#define O_N 128

typedef __attribute__((ext_vector_type(8))) short short8;  // 8 bf16, 4 VGPRs
typedef __attribute__((ext_vector_type(4))) float f32x4;

__device__ __forceinline__ unsigned short f2bf(float f) {
  union { float f; uint32_t u; } v; v.f = f;
  uint32_t u = v.u;
  u += 0x7FFFu + ((u >> 16) & 1u);   // round-to-nearest-even
  return (unsigned short)(u >> 16);
}

// f32 -> bf16 vectorized convert (X0, W3)
__global__ __launch_bounds__(256) void cvt_bf16_k(const float* __restrict__ x,
                                                  unsigned short* __restrict__ y, int n4) {
  int i = blockIdx.x * 256 + threadIdx.x;
  if (i < n4) {
    float4 v = reinterpret_cast<const float4*>(x)[i];
    ushort4 o;
    o.x = f2bf(v.x); o.y = f2bf(v.y); o.z = f2bf(v.z); o.w = f2bf(v.w);
    reinterpret_cast<ushort4*>(y)[i] = o;
  }
}

// W [128][39*Mv] f32 -> fragment-contiguous bf16 (layers 1/2):
// y[ ((((h*KS+kk)*4 + wave)*2 + p)*64 + lane)*8 + j ]
//   = W[ wave*32+p*16+(lane&15) ][ h*Mv + kk*32+(lane>>4)*8+j ]   (0 if m>=Mv)
template <int KS, int Mv>
__global__ __launch_bounds__(256) void repack_wf_k(const float* __restrict__ w,
                                                   unsigned short* __restrict__ y, int total) {
  int idx = blockIdx.x * 256 + threadIdx.x;
  if (idx >= total) return;
  int j = idx & 7, lane = (idx >> 3) & 63, p = (idx >> 9) & 1, wv = (idx >> 10) & 3;
  int kkh = idx >> 12, kk = kkh % KS, h = kkh / KS;
  int o = wv * 32 + p * 16 + (lane & 15);
  int m = kk * 32 + (lane >> 4) * 8 + j;
  float v = (m < Mv) ? w[(size_t)o * (39 * Mv) + h * Mv + m] : 0.f;
  y[idx] = f2bf(v);
}

// MP: padded channel count of Xi (64 layer1, 128 layer2); KS = MP/32
template <int MP, int LOFF, bool WRITE_X>
__global__ __launch_bounds__(256, 2) void cin_layer_k(
    const unsigned short* __restrict__ Xib, int Mv,            // [B][Mv][64] bf16
    const unsigned short* __restrict__ Wfrag,                  // fragment-packed bf16
    const float* __restrict__ X0f,                             // [B][39][64] f32
    const float* __restrict__ bias,                            // [128] f32
    unsigned short* __restrict__ Xnext,                        // [B][128][64] bf16
    float* __restrict__ out)                                   // [B][384] f32
{
  constexpr int KS = MP / 32;
  __shared__ __align__(16) unsigned short xi_t[8192]; // 16 KB, [d][m] XOR-swizzled
  __shared__ float x0s[F_N * D_N];                    // [h][d] f32

  const int b = blockIdx.x;
  const int t = threadIdx.x;

  // ---- stage Xi transposed+swizzled, X0 fp32 ----
  {
    const int d = t & 63, m0 = t >> 6;
    const unsigned short* src = Xib + (size_t)b * Mv * 64;
    #pragma unroll
    for (int m = m0; m < MP; m += 4) {
      unsigned short v = (m < Mv) ? src[m * 64 + d] : (unsigned short)0;
      int off = (d * (MP * 2) + m * 2) ^ ((d & 7) << 4);
      *(unsigned short*)((char*)xi_t + off) = v;
    }
    const float* xs = X0f + (size_t)b * (F_N * D_N);
    for (int i = t; i < F_N * D_N; i += 256) x0s[i] = xs[i];
  }
  __syncthreads();

  const int wave = t >> 6, lane = t & 63, lr = lane & 15, lg = lane >> 4;
  const f32x4 zero4 = {0.f, 0.f, 0.f, 0.f};

  // ---- hoist B-fragments (h-invariant!): bbr[kk][nf] ----
  short8 bbr[KS][4];
  #pragma unroll
  for (int kk = 0; kk < KS; ++kk)
    #pragma unroll
    for (int nf = 0; nf < 4; ++nf) {
      const int n = nf * 16 + lr;
      const int off = (n * (MP * 2) + (kk * 32 + lg * 8) * 2) ^ ((n & 7) << 4);
      bbr[kk][nf] = *(const short8*)((const char*)xi_t + off);
    }

  f32x4 accO[2][4];
  #pragma unroll
  for (int p = 0; p < 2; ++p)
    #pragma unroll
    for (int nf = 0; nf < 4; ++nf) accO[p][nf] = zero4;

  const short8* Wf = (const short8*)Wfrag;
  const int wbase = wave * 128 + lane;

  short8 wA[KS][2], wB[KS][2];

  auto loadW = [&](short8 (&buf)[KS][2], int hh) {
    const short8* pw = Wf + (size_t)hh * (KS * 512) + wbase;
    #pragma unroll
    for (int kk = 0; kk < KS; ++kk)
      #pragma unroll
      for (int p = 0; p < 2; ++p)
        buf[kk][p] = pw[kk * 512 + p * 64];
  };

  auto body = [&](short8 (&buf)[KS][2], int h) {
    f32x4 accP[2][4];
    #pragma unroll
    for (int p = 0; p < 2; ++p)
      #pragma unroll
      for (int nf = 0; nf < 4; ++nf)
        accP[p][nf] = __builtin_amdgcn_mfma_f32_16x16x32_bf16(buf[0][p], bbr[0][nf], zero4, 0, 0, 0);
    #pragma unroll
    for (int kk = 1; kk < KS; ++kk)
      #pragma unroll
      for (int p = 0; p < 2; ++p)
        #pragma unroll
        for (int nf = 0; nf < 4; ++nf)
          accP[p][nf] = __builtin_amdgcn_mfma_f32_16x16x32_bf16(buf[kk][p], bbr[kk][nf], accP[p][nf], 0, 0, 0);
    #pragma unroll
    for (int nf = 0; nf < 4; ++nf) {
      const float s = x0s[h * 64 + nf * 16 + lr];
      #pragma unroll
      for (int p = 0; p < 2; ++p)
        #pragma unroll
        for (int r = 0; r < 4; ++r) accO[p][nf][r] += s * accP[p][nf][r];
    }
  };

  // ---- software-pipelined h-loop (static 2-buffer, unroll-2) ----
  loadW(wA, 0);
  for (int h = 0; h < F_N; h += 2) {
    loadW(wB, (h + 1 < F_N) ? h + 1 : F_N - 1);
    body(wA, h);
    loadW(wA, (h + 2 < F_N) ? h + 2 : F_N - 1);
    if (h + 1 < F_N) body(wB, h + 1);
  }

  // ---- epilogue ----
  float bv[2][4];
  #pragma unroll
  for (int p = 0; p < 2; ++p)
    #pragma unroll
    for (int r = 0; r < 4; ++r) bv[p][r] = bias[wave * 32 + p * 16 + lg * 4 + r];

  if (WRITE_X) {
    __syncthreads();
    unsigned short* xo = xi_t;
    #pragma unroll
    for (int p = 0; p < 2; ++p)
      #pragma unroll
      for (int nf = 0; nf < 4; ++nf)
        #pragma unroll
        for (int r = 0; r < 4; ++r) {
          int o = wave * 32 + p * 16 + lg * 4 + r;
          xo[o * 64 + nf * 16 + lr] = f2bf(accO[p][nf][r] + bv[p][r]);
        }
    __syncthreads();
    const uint4* s4 = (const uint4*)xo;
    uint4* d4 = (uint4*)(Xnext + (size_t)b * (O_N * D_N));
    for (int i = t; i < 1024; i += 256) d4[i] = s4[i];
  }

  #pragma unroll
  for (int p = 0; p < 2; ++p)
    #pragma unroll
    for (int r = 0; r < 4; ++r) {
      float v = accO[p][0][r] + accO[p][1][r] + accO[p][2][r] + accO[p][3][r];
      v += __shfl_xor(v, 1, 16);
      v += __shfl_xor(v, 2, 16);
      v += __shfl_xor(v, 4, 16);
      v += __shfl_xor(v, 8, 16);
      if (lr == 0)
        out[(size_t)b * 384 + LOFF + wave * 32 + p * 16 + lg * 4 + r] = v + 64.0f * bv[p][r];
    }
}

// G[b,h,m] = sum_d X0[b,h,d]*X2[b,m,d]  -> Gb [1024][39*128] bf16
__global__ __launch_bounds__(256) void gram_k(
    const unsigned short* __restrict__ X0b,   // [1024][39][64] bf16
    const unsigned short* __restrict__ X2b,   // [1024][128][64] bf16
    unsigned short* __restrict__ Gb)          // [1024][4992] bf16
{
  const int b = blockIdx.x, t = threadIdx.x;
  const int wave = t >> 6, lane = t & 63, lr = lane & 15, lg = lane >> 4;
  const f32x4 zero4 = {0.f, 0.f, 0.f, 0.f};

  const unsigned short* xa = X0b + (size_t)b * 2496;
  const unsigned short* xc = X2b + (size_t)b * 8192;

  short8 af[3][2], bfr[2][2];
  #pragma unroll
  for (int hf = 0; hf < 3; ++hf)       // A row = h (rows 39..47 garbage, masked at store)
    #pragma unroll
    for (int kk = 0; kk < 2; ++kk)
      af[hf][kk] = *(const short8*)(xa + (hf * 16 + lr) * 64 + kk * 32 + lg * 8);
  #pragma unroll
  for (int mf = 0; mf < 2; ++mf)       // B col = m
    #pragma unroll
    for (int kk = 0; kk < 2; ++kk)
      bfr[mf][kk] = *(const short8*)(xc + (wave * 32 + mf * 16 + lr) * 64 + kk * 32 + lg * 8);

  f32x4 acc[3][2];
  #pragma unroll
  for (int hf = 0; hf < 3; ++hf)
    #pragma unroll
    for (int mf = 0; mf < 2; ++mf) {
      acc[hf][mf] = __builtin_amdgcn_mfma_f32_16x16x32_bf16(af[hf][0], bfr[mf][0], zero4, 0, 0, 0);
      acc[hf][mf] = __builtin_amdgcn_mfma_f32_16x16x32_bf16(af[hf][1], bfr[mf][1], acc[hf][mf], 0, 0, 0);
    }

  // D: row(h) = hf*16 + lg*4 + r, col(m) = wave*32 + mf*16 + lr
  #pragma unroll
  for (int hf = 0; hf < 3; ++hf)
    #pragma unroll
    for (int mf = 0; mf < 2; ++mf)
      #pragma unroll
      for (int r = 0; r < 4; ++r) {
        int h = hf * 16 + lg * 4 + r;
        if (h < F_N)
          Gb[(size_t)b * 4992 + h * 128 + wave * 32 + mf * 16 + lr] = f2bf(acc[hf][mf][r]);
      }
}

// pooled3[b,o] = sum_k W3[o,k]*G[b,k] + 64*b3[o]; K=4992=156*32
__global__ __launch_bounds__(256) void pooled3_k(
    const unsigned short* __restrict__ Gb,    // [1024][4992] bf16
    const unsigned short* __restrict__ W3p,   // [128][4992] bf16
    const float* __restrict__ b3,             // [128] f32
    float* __restrict__ out)                  // [1024][384] f32
{
  const int b0 = blockIdx.x * 16, t = threadIdx.x;
  const int wave = t >> 6, lane = t & 63, lr = lane & 15, lg = lane >> 4;
  const f32x4 zero4 = {0.f, 0.f, 0.f, 0.f};

  const unsigned short* ga = Gb + (size_t)(b0 + lr) * 4992 + lg * 8;        // A row = b
  const unsigned short* w0 = W3p + (size_t)(wave * 32 + lr) * 4992 + lg * 8; // B col = o
  const unsigned short* w1 = w0 + (size_t)16 * 4992;

  f32x4 acc0 = zero4, acc1 = zero4;
  #pragma unroll 4
  for (int ks = 0; ks < 156; ++ks) {
    short8 a  = *(const short8*)(ga + ks * 32);
    short8 q0 = *(const short8*)(w0 + ks * 32);
    short8 q1 = *(const short8*)(w1 + ks * 32);
    acc0 = __builtin_amdgcn_mfma_f32_16x16x32_bf16(a, q0, acc0, 0, 0, 0);
    acc1 = __builtin_amdgcn_mfma_f32_16x16x32_bf16(a, q1, acc1, 0, 0, 0);
  }

  // D: row(b) = lg*4 + r, col(o) = lr (+ frag offset)
  #pragma unroll
  for (int r = 0; r < 4; ++r) {
    int bb = b0 + lg * 4 + r;
    int o0 = wave * 32 + lr;
    out[(size_t)bb * 384 + 256 + o0]      = acc0[r] + 64.0f * b3[o0];
    out[(size_t)bb * 384 + 256 + o0 + 16] = acc1[r] + 64.0f * b3[o0 + 16];
  }
}

extern "C" void kernel_launch(void* const* d_in, const int* in_sizes, int n_in,
                              void* d_out, int out_size, void* d_ws, size_t ws_size,
                              hipStream_t stream) {
  const float* X0 = (const float*)d_in[0];
  const float* W1 = (const float*)d_in[1];
  const float* b1 = (const float*)d_in[2];
  const float* W2 = (const float*)d_in[3];
  const float* b2 = (const float*)d_in[4];
  const float* W3 = (const float*)d_in[5];
  const float* b3 = (const float*)d_in[6];
  float* out = (float*)d_out;

  // ws layout (bf16 elements) — identical to round 6 (~42 MB)
  unsigned short* X0b = (unsigned short*)d_ws;      // 1024*39*64   = 2555904
  unsigned short* W1f = X0b + 2555904;              // 39*2*4096    = 319488
  unsigned short* W2f = W1f + 319488;               // 39*4*4096    = 638976
  unsigned short* W3p = W2f + 638976;               // 128*4992     = 638976 (plain bf16)
  unsigned short* X1b = W3p + 638976;               // 1024*128*64  = 8388608
  unsigned short* X2b = X1b + 8388608;
  unsigned short* Gb  = X1b;                        // alias: X1b free after layer 2

  cvt_bf16_k<<<2496, 256, 0, stream>>>(X0, X0b, 638976);
  repack_wf_k<2, 39><<<1248, 256, 0, stream>>>(W1, W1f, 319488);
  repack_wf_k<4, 128><<<2496, 256, 0, stream>>>(W2, W2f, 638976);
  cvt_bf16_k<<<624, 256, 0, stream>>>(W3, W3p, 159744);

  cin_layer_k<64, 0, true><<<1024, 256, 0, stream>>>(X0b, 39, W1f, X0, b1, X1b, out);
  cin_layer_k<128, 128, true><<<1024, 256, 0, stream>>>(X1b, 128, W2f, X0, b2, X2b, out);
  gram_k<<<1024, 256, 0, stream>>>(X0b, X2b, Gb);
  pooled3_k<<<64, 256, 0, stream>>>(Gb, W3p, b3, out);
}

// Round 8
// 285.004 us; speedup vs baseline: 2.1706x; 1.0232x over previous
//
#include <hip/hip_runtime.h>
#include <stdint.h>

// CIN (xDeepFM): B=1024, F=39, D=64, UNITS=[128,128,128]
// Layers 1/2: Out[o,d] = sum_h (W_h @ (x0_h[d] * Xi))[o,d]  -- x0 scale folded
//   into the MFMA B-operand via v_pk_mul_f16; ONE persistent accumulator
//   across all h (no per-h accP / fp32 scale pass).  All-f16 operands.
// Layer 3 (pooled-only) collapsed: pooled3[b,o] = sum_k W3[o,k]*G[b,k],
//   G[b,h,m] = sum_d X0[b,h,d]*X2[b,m,d].

#define F_N 39
#define D_N 64
#define O_N 128

typedef _Float16 f16;
typedef _Float16 f16x8 __attribute__((ext_vector_type(8)));
typedef _Float16 f16x4 __attribute__((ext_vector_type(4)));
typedef float f32x4 __attribute__((ext_vector_type(4)));

__device__ __forceinline__ unsigned short h2u(f16 h) {
  union { f16 h; unsigned short u; } v; v.h = h; return v.u;
}

// f32 -> f16 vectorized convert (X0, W3)
__global__ __launch_bounds__(256) void cvt_f16_k(const float* __restrict__ x,
                                                 f16* __restrict__ y, int n4) {
  int i = blockIdx.x * 256 + threadIdx.x;
  if (i < n4) {
    float4 v = reinterpret_cast<const float4*>(x)[i];
    f16x4 o = {(f16)v.x, (f16)v.y, (f16)v.z, (f16)v.w};
    reinterpret_cast<f16x4*>(y)[i] = o;
  }
}

// W [128][39*Mv] f32 -> fragment-contiguous f16:
// y[ ((((h*KS+kk)*4 + wave)*2 + p)*64 + lane)*8 + j ]
//   = W[ wave*32+p*16+(lane&15) ][ h*Mv + kk*32+(lane>>4)*8+j ]   (0 if m>=Mv)
template <int KS, int Mv>
__global__ __launch_bounds__(256) void repack_wf_k(const float* __restrict__ w,
                                                   f16* __restrict__ y, int total) {
  int idx = blockIdx.x * 256 + threadIdx.x;
  if (idx >= total) return;
  int j = idx & 7, lane = (idx >> 3) & 63, p = (idx >> 9) & 1, wv = (idx >> 10) & 3;
  int kkh = idx >> 12, kk = kkh % KS, h = kkh / KS;
  int o = wv * 32 + p * 16 + (lane & 15);
  int m = kk * 32 + (lane >> 4) * 8 + j;
  y[idx] = (m < Mv) ? (f16)w[(size_t)o * (39 * Mv) + h * Mv + m] : (f16)0.f;
}

// MP: padded channel count of Xi (64 layer1, 128 layer2); KS = MP/32
template <int MP, int LOFF, bool WRITE_X>
__global__ __launch_bounds__(256, 2) void cin_layer_k(
    const f16* __restrict__ Xib, int Mv,              // [B][Mv][64] f16
    const f16* __restrict__ Wfrag,                    // fragment-packed f16
    const float* __restrict__ X0f,                    // [B][39][64] f32
    const float* __restrict__ bias,                   // [128] f32
    f16* __restrict__ Xnext,                          // [B][128][64] f16
    float* __restrict__ out)                          // [B][384] f32
{
  constexpr int KS = MP / 32;
  __shared__ __align__(16) unsigned short xi_t[8192]; // 16 KB, [d][m] f16 bits, XOR-swizzled
  __shared__ f16 x0s[F_N * D_N];                      // 4992 B: [h][d] f16

  const int b = blockIdx.x;
  const int t = threadIdx.x;

  // ---- stage Xi transposed+swizzled (bit copy), X0 -> f16 ----
  {
    const int d = t & 63, m0 = t >> 6;
    const unsigned short* src = (const unsigned short*)(Xib + (size_t)b * Mv * 64);
    #pragma unroll
    for (int m = m0; m < MP; m += 4) {
      unsigned short v = (m < Mv) ? src[m * 64 + d] : (unsigned short)0;
      int off = (d * (MP * 2) + m * 2) ^ ((d & 7) << 4);
      *(unsigned short*)((char*)xi_t + off) = v;
    }
    const float* xs = X0f + (size_t)b * (F_N * D_N);
    for (int i = t; i < F_N * D_N; i += 256) x0s[i] = (f16)xs[i];
  }
  __syncthreads();

  const int wave = t >> 6, lane = t & 63, lr = lane & 15, lg = lane >> 4;
  const f32x4 zero4 = {0.f, 0.f, 0.f, 0.f};

  // ---- hoist raw Xi B-fragments (h-invariant): bbr[kk][nf] ----
  f16x8 bbr[KS][4];
  #pragma unroll
  for (int kk = 0; kk < KS; ++kk)
    #pragma unroll
    for (int nf = 0; nf < 4; ++nf) {
      const int n = nf * 16 + lr;
      const int off = (n * (MP * 2) + (kk * 32 + lg * 8) * 2) ^ ((n & 7) << 4);
      bbr[kk][nf] = *(const f16x8*)((const char*)xi_t + off);
    }

  // ---- ONE persistent accumulator across all h ----
  f32x4 accO[2][4];
  #pragma unroll
  for (int p = 0; p < 2; ++p)
    #pragma unroll
    for (int nf = 0; nf < 4; ++nf) accO[p][nf] = zero4;

  const f16x8* Wf = (const f16x8*)Wfrag;
  const int wbase = wave * 128 + lane;

  f16x8 wA[KS][2], wB[KS][2];

  auto loadW = [&](f16x8 (&buf)[KS][2], int hh) {
    const f16x8* pw = Wf + (size_t)hh * (KS * 512) + wbase;
    #pragma unroll
    for (int kk = 0; kk < KS; ++kk)
      #pragma unroll
      for (int p = 0; p < 2; ++p)
        buf[kk][p] = pw[kk * 512 + p * 64];
  };

  auto body = [&](f16x8 (&buf)[KS][2], int h) {
    f16 sv[4];
    #pragma unroll
    for (int nf = 0; nf < 4; ++nf) sv[nf] = x0s[h * 64 + nf * 16 + lr];
    #pragma unroll
    for (int kk = 0; kk < KS; ++kk)
      #pragma unroll
      for (int nf = 0; nf < 4; ++nf) {
        f16x8 sb = bbr[kk][nf] * sv[nf];   // 4x v_pk_mul_f16: B' = x0*Xi
        accO[0][nf] = __builtin_amdgcn_mfma_f32_16x16x32_f16(buf[kk][0], sb, accO[0][nf], 0, 0, 0);
        accO[1][nf] = __builtin_amdgcn_mfma_f32_16x16x32_f16(buf[kk][1], sb, accO[1][nf], 0, 0, 0);
      }
  };

  // ---- software-pipelined h-loop (static 2-buffer, unroll-2) ----
  loadW(wA, 0);
  for (int h = 0; h < F_N; h += 2) {
    loadW(wB, (h + 1 < F_N) ? h + 1 : F_N - 1);
    body(wA, h);
    loadW(wA, (h + 2 < F_N) ? h + 2 : F_N - 1);
    if (h + 1 < F_N) body(wB, h + 1);
  }

  // ---- epilogue ----
  float bv[2][4];
  #pragma unroll
  for (int p = 0; p < 2; ++p)
    #pragma unroll
    for (int r = 0; r < 4; ++r) bv[p][r] = bias[wave * 32 + p * 16 + lg * 4 + r];

  if (WRITE_X) {
    __syncthreads();  // xi_t reuse as [128][64] f16-bits staging
    unsigned short* xo = xi_t;
    #pragma unroll
    for (int p = 0; p < 2; ++p)
      #pragma unroll
      for (int nf = 0; nf < 4; ++nf)
        #pragma unroll
        for (int r = 0; r < 4; ++r) {
          int o = wave * 32 + p * 16 + lg * 4 + r;
          xo[o * 64 + nf * 16 + lr] = h2u((f16)(accO[p][nf][r] + bv[p][r]));
        }
    __syncthreads();
    const uint4* s4 = (const uint4*)xo;
    uint4* d4 = (uint4*)(Xnext + (size_t)b * (O_N * D_N));
    for (int i = t; i < 1024; i += 256) d4[i] = s4[i];
  }

  #pragma unroll
  for (int p = 0; p < 2; ++p)
    #pragma unroll
    for (int r = 0; r < 4; ++r) {
      float v = accO[p][0][r] + accO[p][1][r] + accO[p][2][r] + accO[p][3][r];
      v += __shfl_xor(v, 1, 16);
      v += __shfl_xor(v, 2, 16);
      v += __shfl_xor(v, 4, 16);
      v += __shfl_xor(v, 8, 16);
      if (lr == 0)
        out[(size_t)b * 384 + LOFF + wave * 32 + p * 16 + lg * 4 + r] = v + 64.0f * bv[p][r];
    }
}

// G[b,h,m] = sum_d X0[b,h,d]*X2[b,m,d]  -> Gb [1024][39*128] f16
__global__ __launch_bounds__(256) void gram_k(
    const f16* __restrict__ X0b,   // [1024][39][64] f16
    const f16* __restrict__ X2b,   // [1024][128][64] f16
    f16* __restrict__ Gb)          // [1024][4992] f16
{
  const int b = blockIdx.x, t = threadIdx.x;
  const int wave = t >> 6, lane = t & 63, lr = lane & 15, lg = lane >> 4;
  const f32x4 zero4 = {0.f, 0.f, 0.f, 0.f};

  const f16* xa = X0b + (size_t)b * 2496;
  const f16* xc = X2b + (size_t)b * 8192;

  f16x8 af[3][2], bfr[2][2];
  #pragma unroll
  for (int hf = 0; hf < 3; ++hf)       // A row = h (rows 39..47 garbage, masked at store)
    #pragma unroll
    for (int kk = 0; kk < 2; ++kk)
      af[hf][kk] = *(const f16x8*)(xa + (hf * 16 + lr) * 64 + kk * 32 + lg * 8);
  #pragma unroll
  for (int mf = 0; mf < 2; ++mf)       // B col = m
    #pragma unroll
    for (int kk = 0; kk < 2; ++kk)
      bfr[mf][kk] = *(const f16x8*)(xc + (wave * 32 + mf * 16 + lr) * 64 + kk * 32 + lg * 8);

  f32x4 acc[3][2];
  #pragma unroll
  for (int hf = 0; hf < 3; ++hf)
    #pragma unroll
    for (int mf = 0; mf < 2; ++mf) {
      acc[hf][mf] = __builtin_amdgcn_mfma_f32_16x16x32_f16(af[hf][0], bfr[mf][0], zero4, 0, 0, 0);
      acc[hf][mf] = __builtin_amdgcn_mfma_f32_16x16x32_f16(af[hf][1], bfr[mf][1], acc[hf][mf], 0, 0, 0);
    }

  // D: row(h) = hf*16 + lg*4 + r, col(m) = wave*32 + mf*16 + lr
  #pragma unroll
  for (int hf = 0; hf < 3; ++hf)
    #pragma unroll
    for (int mf = 0; mf < 2; ++mf)
      #pragma unroll
      for (int r = 0; r < 4; ++r) {
        int h = hf * 16 + lg * 4 + r;
        if (h < F_N)
          Gb[(size_t)b * 4992 + h * 128 + wave * 32 + mf * 16 + lr] = (f16)acc[hf][mf][r];
      }
}

// pooled3[b,o] = sum_k W3[o,k]*G[b,k] + 64*b3[o]; K=4992=156*32
__global__ __launch_bounds__(256) void pooled3_k(
    const f16* __restrict__ Gb,    // [1024][4992] f16
    const f16* __restrict__ W3p,   // [128][4992] f16
    const float* __restrict__ b3,  // [128] f32
    float* __restrict__ out)       // [1024][384] f32
{
  const int b0 = blockIdx.x * 16, t = threadIdx.x;
  const int wave = t >> 6, lane = t & 63, lr = lane & 15, lg = lane >> 4;
  const f32x4 zero4 = {0.f, 0.f, 0.f, 0.f};

  const f16* ga = Gb + (size_t)(b0 + lr) * 4992 + lg * 8;          // A row = b
  const f16* w0 = W3p + (size_t)(wave * 32 + lr) * 4992 + lg * 8;  // B col = o
  const f16* w1 = w0 + (size_t)16 * 4992;

  f32x4 acc0 = zero4, acc1 = zero4;
  #pragma unroll 4
  for (int ks = 0; ks < 156; ++ks) {
    f16x8 a  = *(const f16x8*)(ga + ks * 32);
    f16x8 q0 = *(const f16x8*)(w0 + ks * 32);
    f16x8 q1 = *(const f16x8*)(w1 + ks * 32);
    acc0 = __builtin_amdgcn_mfma_f32_16x16x32_f16(a, q0, acc0, 0, 0, 0);
    acc1 = __builtin_amdgcn_mfma_f32_16x16x32_f16(a, q1, acc1, 0, 0, 0);
  }

  #pragma unroll
  for (int r = 0; r < 4; ++r) {
    int bb = b0 + lg * 4 + r;
    int o0 = wave * 32 + lr;
    out[(size_t)bb * 384 + 256 + o0]      = acc0[r] + 64.0f * b3[o0];
    out[(size_t)bb * 384 + 256 + o0 + 16] = acc1[r] + 64.0f * b3[o0 + 16];
  }
}

extern "C" void kernel_launch(void* const* d_in, const int* in_sizes, int n_in,
                              void* d_out, int out_size, void* d_ws, size_t ws_size,
                              hipStream_t stream) {
  const float* X0 = (const float*)d_in[0];
  const float* W1 = (const float*)d_in[1];
  const float* b1 = (const float*)d_in[2];
  const float* W2 = (const float*)d_in[3];
  const float* b2 = (const float*)d_in[4];
  const float* W3 = (const float*)d_in[5];
  const float* b3 = (const float*)d_in[6];
  float* out = (float*)d_out;

  // ws layout (f16 elements) — same footprint as before (~42 MB)
  f16* X0b = (f16*)d_ws;            // 1024*39*64   = 2555904
  f16* W1f = X0b + 2555904;         // 39*2*4096    = 319488
  f16* W2f = W1f + 319488;          // 39*4*4096    = 638976
  f16* W3p = W2f + 638976;          // 128*4992     = 638976 (plain f16)
  f16* X1b = W3p + 638976;          // 1024*128*64  = 8388608
  f16* X2b = X1b + 8388608;
  f16* Gb  = X1b;                   // alias: X1b free after layer 2

  cvt_f16_k<<<2496, 256, 0, stream>>>(X0, X0b, 638976);
  repack_wf_k<2, 39><<<1248, 256, 0, stream>>>(W1, W1f, 319488);
  repack_wf_k<4, 128><<<2496, 256, 0, stream>>>(W2, W2f, 638976);
  cvt_f16_k<<<624, 256, 0, stream>>>(W3, W3p, 159744);

  cin_layer_k<64, 0, true><<<1024, 256, 0, stream>>>(X0b, 39, W1f, X0, b1, X1b, out);
  cin_layer_k<128, 128, true><<<1024, 256, 0, stream>>>(X1b, 128, W2f, X0, b2, X2b, out);
  gram_k<<<1024, 256, 0, stream>>>(X0b, X2b, Gb);
  pooled3_k<<<64, 256, 0, stream>>>(Gb, W3p, b3, out);
}

// Round 9
// 254.028 us; speedup vs baseline: 2.4353x; 1.1219x over previous
//
#include <hip/hip_runtime.h>
#include <stdint.h>

// CIN (xDeepFM): B=1024, F=39, D=64, UNITS=[128,128,128]
// ONE fused kernel per b: L1 -> (X1^T kept in LDS) -> L2 -> (X2 kept in LDS)
// -> gram G=X0·X2^T.  pooled3[b,o] = sum_k W3[o,k]*G[b,k] in a second kernel.
// x0 scale folded into MFMA B-operand (v_pk_mul_f16), persistent accumulator.

#define F_N 39
#define D_N 64
#define O_N 128

typedef _Float16 f16;
typedef _Float16 f16x8 __attribute__((ext_vector_type(8)));
typedef _Float16 f16x4 __attribute__((ext_vector_type(4)));
typedef float f32x4 __attribute__((ext_vector_type(4)));

__device__ __forceinline__ unsigned short h2u(f16 h) {
  union { f16 h; unsigned short u; } v; v.h = h; return v.u;
}

// ---- prep: repack W1/W2 to MFMA-fragment layout, cvt W3 (one kernel) ----
__device__ __forceinline__ void repack_one(const float* __restrict__ w,
                                           f16* __restrict__ y, int idx, int KS, int Mv) {
  int j = idx & 7, lane = (idx >> 3) & 63, p = (idx >> 9) & 1, wv = (idx >> 10) & 3;
  int kkh = idx >> 12, kk = kkh % KS, h = kkh / KS;
  int o = wv * 32 + p * 16 + (lane & 15);
  int m = kk * 32 + (lane >> 4) * 8 + j;
  y[idx] = (m < Mv) ? (f16)w[(size_t)o * (39 * Mv) + h * Mv + m] : (f16)0.f;
}

__global__ __launch_bounds__(256) void prep_k(const float* __restrict__ W1,
                                              const float* __restrict__ W2,
                                              const float* __restrict__ W3,
                                              f16* __restrict__ W1f,
                                              f16* __restrict__ W2f,
                                              f16* __restrict__ W3p) {
  int blk = blockIdx.x, t = threadIdx.x;
  if (blk < 1248) {
    repack_one(W1, W1f, blk * 256 + t, 2, 39);
  } else if (blk < 3744) {
    repack_one(W2, W2f, (blk - 1248) * 256 + t, 4, 128);
  } else {
    int i = (blk - 3744) * 256 + t;   // 624 blocks * 256 = 159744 float4
    float4 v = reinterpret_cast<const float4*>(W3)[i];
    f16x4 o = {(f16)v.x, (f16)v.y, (f16)v.z, (f16)v.w};
    reinterpret_cast<f16x4*>(W3p)[i] = o;
  }
}

// One CIN layer: bbr from swizzled xi_t (MP=KS*32), stream W frags, persistent acc.
// Contains a barrier after the bbr reads so the caller may overwrite xi_t after.
template <int KS>
__device__ __forceinline__ void layer_mm(const f16* __restrict__ Wf_base,
                                         const unsigned short* xi_t,
                                         const f16* x0s,
                                         f32x4 (&accO)[2][4],
                                         int wave, int lane, int lr, int lg) {
  constexpr int MP = KS * 32;
  f16x8 bbr[KS][4];
  #pragma unroll
  for (int kk = 0; kk < KS; ++kk)
    #pragma unroll
    for (int nf = 0; nf < 4; ++nf) {
      const int n = nf * 16 + lr;
      const int off = (n * (MP * 2) + (kk * 32 + lg * 8) * 2) ^ ((n & 7) << 4);
      bbr[kk][nf] = *(const f16x8*)((const char*)xi_t + off);
    }
  __syncthreads();   // all xi_t reads complete before caller overwrites it

  const f16x8* Wf = (const f16x8*)Wf_base;
  const int wbase = wave * 128 + lane;
  f16x8 wA[KS][2], wB[KS][2];

  auto loadW = [&](f16x8 (&buf)[KS][2], int hh) {
    const f16x8* pw = Wf + (size_t)hh * (KS * 512) + wbase;
    #pragma unroll
    for (int kk = 0; kk < KS; ++kk)
      #pragma unroll
      for (int p = 0; p < 2; ++p)
        buf[kk][p] = pw[kk * 512 + p * 64];
  };

  auto body = [&](f16x8 (&buf)[KS][2], int h) {
    f16 sv[4];
    #pragma unroll
    for (int nf = 0; nf < 4; ++nf) sv[nf] = x0s[h * 64 + nf * 16 + lr];
    #pragma unroll
    for (int kk = 0; kk < KS; ++kk)
      #pragma unroll
      for (int nf = 0; nf < 4; ++nf) {
        f16x8 sb = bbr[kk][nf] * sv[nf];   // v_pk_mul_f16: B' = x0*Xi
        accO[0][nf] = __builtin_amdgcn_mfma_f32_16x16x32_f16(buf[kk][0], sb, accO[0][nf], 0, 0, 0);
        accO[1][nf] = __builtin_amdgcn_mfma_f32_16x16x32_f16(buf[kk][1], sb, accO[1][nf], 0, 0, 0);
      }
  };

  loadW(wA, 0);
  for (int h = 0; h < F_N; h += 2) {
    loadW(wB, (h + 1 < F_N) ? h + 1 : F_N - 1);
    body(wA, h);
    loadW(wA, (h + 2 < F_N) ? h + 2 : F_N - 1);
    if (h + 1 < F_N) body(wB, h + 1);
  }
}

__global__ __launch_bounds__(256, 2) void cin_fused_k(
    const float* __restrict__ X0f,    // [1024][39][64] f32
    const f16* __restrict__ W1f,      // frag-packed [39][2][4][2][64][8]
    const f16* __restrict__ W2f,      // frag-packed [39][4][4][2][64][8]
    const float* __restrict__ b1,
    const float* __restrict__ b2,
    f16* __restrict__ Gb,             // [1024][4992] f16
    float* __restrict__ out)          // [1024][384] f32
{
  __shared__ __align__(16) unsigned short xi_t[8192];  // X0^T (MP=64) then X1^T (MP=128), swizzled
  __shared__ __align__(16) unsigned short xbuf[8192];  // X2 [128][64] f16-bits
  __shared__ f16 x0s[48 * 64];                         // [h][d], rows 39..47 zero

  const int b = blockIdx.x, t = threadIdx.x;
  const int wave = t >> 6, lane = t & 63, lr = lane & 15, lg = lane >> 4;
  const f32x4 zero4 = {0.f, 0.f, 0.f, 0.f};
  const float* xs = X0f + (size_t)b * (F_N * D_N);

  // ---- phase A: stage X0^T (swizzled, m-padded to 64) + x0s f16 ----
  {
    const int d = t & 63, m0 = t >> 6;
    #pragma unroll
    for (int m = m0; m < 64; m += 4) {
      f16 v = (m < F_N) ? (f16)xs[m * 64 + d] : (f16)0.f;
      int off = (d * 128 + m * 2) ^ ((d & 7) << 4);
      *(unsigned short*)((char*)xi_t + off) = h2u(v);
    }
    for (int i = t; i < 3072; i += 256)
      x0s[i] = (i < F_N * D_N) ? (f16)xs[i] : (f16)0.f;
  }
  __syncthreads();

  // ---- layer 1 ----
  f32x4 accO[2][4];
  #pragma unroll
  for (int p = 0; p < 2; ++p)
    #pragma unroll
    for (int nf = 0; nf < 4; ++nf) accO[p][nf] = zero4;
  layer_mm<2>(W1f, xi_t, x0s, accO, wave, lane, lr, lg);

  // epilogue 1: X1^T directly into xi_t (transposed+swizzled, MP=128); pooled1
  {
    float bv[2][4];
    #pragma unroll
    for (int p = 0; p < 2; ++p)
      #pragma unroll
      for (int r = 0; r < 4; ++r) bv[p][r] = b1[wave * 32 + p * 16 + lg * 4 + r];

    #pragma unroll
    for (int p = 0; p < 2; ++p)
      #pragma unroll
      for (int nf = 0; nf < 4; ++nf)
        #pragma unroll
        for (int r = 0; r < 4; ++r) {
          int o = wave * 32 + p * 16 + lg * 4 + r;   // m-index of X1
          int d = nf * 16 + lr;
          f16 val = (f16)(accO[p][nf][r] + bv[p][r]);
          int off = (d * 256 + o * 2) ^ ((d & 7) << 4);
          *(unsigned short*)((char*)xi_t + off) = h2u(val);
        }

    #pragma unroll
    for (int p = 0; p < 2; ++p)
      #pragma unroll
      for (int r = 0; r < 4; ++r) {
        float v = accO[p][0][r] + accO[p][1][r] + accO[p][2][r] + accO[p][3][r];
        v += __shfl_xor(v, 1, 16);
        v += __shfl_xor(v, 2, 16);
        v += __shfl_xor(v, 4, 16);
        v += __shfl_xor(v, 8, 16);
        if (lr == 0)
          out[(size_t)b * 384 + wave * 32 + p * 16 + lg * 4 + r] = v + 64.0f * bv[p][r];
      }
  }
  __syncthreads();   // X1^T visible to all before layer-2 bbr reads

  // ---- layer 2 ----
  #pragma unroll
  for (int p = 0; p < 2; ++p)
    #pragma unroll
    for (int nf = 0; nf < 4; ++nf) accO[p][nf] = zero4;
  layer_mm<4>(W2f, xi_t, x0s, accO, wave, lane, lr, lg);

  // epilogue 2: X2 -> xbuf [o][d]; pooled2
  {
    float bv[2][4];
    #pragma unroll
    for (int p = 0; p < 2; ++p)
      #pragma unroll
      for (int r = 0; r < 4; ++r) bv[p][r] = b2[wave * 32 + p * 16 + lg * 4 + r];

    #pragma unroll
    for (int p = 0; p < 2; ++p)
      #pragma unroll
      for (int nf = 0; nf < 4; ++nf)
        #pragma unroll
        for (int r = 0; r < 4; ++r) {
          int o = wave * 32 + p * 16 + lg * 4 + r;
          int d = nf * 16 + lr;
          xbuf[o * 64 + d] = h2u((f16)(accO[p][nf][r] + bv[p][r]));
        }

    #pragma unroll
    for (int p = 0; p < 2; ++p)
      #pragma unroll
      for (int r = 0; r < 4; ++r) {
        float v = accO[p][0][r] + accO[p][1][r] + accO[p][2][r] + accO[p][3][r];
        v += __shfl_xor(v, 1, 16);
        v += __shfl_xor(v, 2, 16);
        v += __shfl_xor(v, 4, 16);
        v += __shfl_xor(v, 8, 16);
        if (lr == 0)
          out[(size_t)b * 384 + 128 + wave * 32 + p * 16 + lg * 4 + r] = v + 64.0f * bv[p][r];
      }
  }
  __syncthreads();   // X2 visible before gram reads

  // ---- gram: G[h,m] = sum_d X0[h,d]*X2[m,d] ----
  {
    const f16* x2 = (const f16*)xbuf;
    f16x8 af[3][2], bfr[2][2];
    #pragma unroll
    for (int hf = 0; hf < 3; ++hf)     // A row = h (rows 39..47 are zeros)
      #pragma unroll
      for (int kk = 0; kk < 2; ++kk)
        af[hf][kk] = *(const f16x8*)(x0s + (hf * 16 + lr) * 64 + kk * 32 + lg * 8);
    #pragma unroll
    for (int mf = 0; mf < 2; ++mf)     // B col = m
      #pragma unroll
      for (int kk = 0; kk < 2; ++kk)
        bfr[mf][kk] = *(const f16x8*)(x2 + (wave * 32 + mf * 16 + lr) * 64 + kk * 32 + lg * 8);

    f32x4 acc[3][2];
    #pragma unroll
    for (int hf = 0; hf < 3; ++hf)
      #pragma unroll
      for (int mf = 0; mf < 2; ++mf) {
        acc[hf][mf] = __builtin_amdgcn_mfma_f32_16x16x32_f16(af[hf][0], bfr[mf][0], zero4, 0, 0, 0);
        acc[hf][mf] = __builtin_amdgcn_mfma_f32_16x16x32_f16(af[hf][1], bfr[mf][1], acc[hf][mf], 0, 0, 0);
      }

    // D: row(h) = hf*16 + lg*4 + r, col(m) = wave*32 + mf*16 + lr
    #pragma unroll
    for (int hf = 0; hf < 3; ++hf)
      #pragma unroll
      for (int mf = 0; mf < 2; ++mf)
        #pragma unroll
        for (int r = 0; r < 4; ++r) {
          int h = hf * 16 + lg * 4 + r;
          if (h < F_N)
            Gb[(size_t)b * 4992 + h * 128 + wave * 32 + mf * 16 + lr] = (f16)acc[hf][mf][r];
        }
  }
}

// pooled3[b,o] = sum_k W3[o,k]*G[b,k] + 64*b3[o]; K=4992=156*32
__global__ __launch_bounds__(256) void pooled3_k(
    const f16* __restrict__ Gb,    // [1024][4992] f16
    const f16* __restrict__ W3p,   // [128][4992] f16
    const float* __restrict__ b3,  // [128] f32
    float* __restrict__ out)       // [1024][384] f32
{
  const int b0 = blockIdx.x * 16, t = threadIdx.x;
  const int wave = t >> 6, lane = t & 63, lr = lane & 15, lg = lane >> 4;
  const f32x4 zero4 = {0.f, 0.f, 0.f, 0.f};

  const f16* ga = Gb + (size_t)(b0 + lr) * 4992 + lg * 8;          // A row = b
  const f16* w0 = W3p + (size_t)(wave * 32 + lr) * 4992 + lg * 8;  // B col = o
  const f16* w1 = w0 + (size_t)16 * 4992;

  f32x4 acc0 = zero4, acc1 = zero4;
  #pragma unroll 4
  for (int ks = 0; ks < 156; ++ks) {
    f16x8 a  = *(const f16x8*)(ga + ks * 32);
    f16x8 q0 = *(const f16x8*)(w0 + ks * 32);
    f16x8 q1 = *(const f16x8*)(w1 + ks * 32);
    acc0 = __builtin_amdgcn_mfma_f32_16x16x32_f16(a, q0, acc0, 0, 0, 0);
    acc1 = __builtin_amdgcn_mfma_f32_16x16x32_f16(a, q1, acc1, 0, 0, 0);
  }

  #pragma unroll
  for (int r = 0; r < 4; ++r) {
    int bb = b0 + lg * 4 + r;
    int o0 = wave * 32 + lr;
    out[(size_t)bb * 384 + 256 + o0]      = acc0[r] + 64.0f * b3[o0];
    out[(size_t)bb * 384 + 256 + o0 + 16] = acc1[r] + 64.0f * b3[o0 + 16];
  }
}

extern "C" void kernel_launch(void* const* d_in, const int* in_sizes, int n_in,
                              void* d_out, int out_size, void* d_ws, size_t ws_size,
                              hipStream_t stream) {
  const float* X0 = (const float*)d_in[0];
  const float* W1 = (const float*)d_in[1];
  const float* b1 = (const float*)d_in[2];
  const float* W2 = (const float*)d_in[3];
  const float* b2 = (const float*)d_in[4];
  const float* W3 = (const float*)d_in[5];
  const float* b3 = (const float*)d_in[6];
  float* out = (float*)d_out;

  // ws layout (f16 elements), ~13.4 MB total
  f16* W1f = (f16*)d_ws;            // 39*2*4096    = 319488
  f16* W2f = W1f + 319488;          // 39*4*4096    = 638976
  f16* W3p = W2f + 638976;          // 128*4992     = 638976
  f16* Gb  = W3p + 638976;          // 1024*4992    = 5111808

  prep_k<<<4368, 256, 0, stream>>>(W1, W2, W3, W1f, W2f, W3p);
  cin_fused_k<<<1024, 256, 0, stream>>>(X0, W1f, W2f, b1, b2, Gb, out);
  pooled3_k<<<64, 256, 0, stream>>>(Gb, W3p, b3, out);
}